// Round 8
// baseline (391.593 us; speedup 1.0000x reference)
//
#include <hip/hip_runtime.h>

// VGAE GCN encoder: radix-binned CSR build (packed 4B edges) + pre-scaled CSR
// gather aggregation + barrier-free register-dataflow fp16 MFMA GEMMs
// (fragment-major pre-packed weights, B streamed from L2, no LDS in GEMMs).
// n=100000, f=256, hid=128, dout=64, E=1.6M (read from in_sizes).
//
// Algebra (norm-folded): hs = (X@W1)*dis (fp16);
//   agg1: acc_i = hs_i + sum_{s in N(i)} hs_s ; h1s_i = relu(dis_i*acc_i + b1)*dis_i
//   agg2: agg2_i = dis_i*(h1s_i + sum h1s_s)  ; out = agg2 @ [Wmu|Wvar] + bias
//
// Round-6 post-mortem: lane-scattered LDS atomics serialize (20x regression) —
// register accumulation per node is the right CDNA4 structure.

#define HID 128
#define DOUT 64
#define NB_SHIFT 8          // 256 nodes per bucket
#define CHUNK 8192          // edges per binning block
#define MAXNB 400           // max buckets (n <= 102400)

typedef _Float16 half_t;
typedef half_t f16x4 __attribute__((ext_vector_type(4)));
typedef half_t f16x8 __attribute__((ext_vector_type(8)));
typedef float  f32x4 __attribute__((ext_vector_type(4)));

// ==================== CSR build ====================

__global__ __launch_bounds__(256) void bincount_kernel(const int* __restrict__ dst,
                                                       int* __restrict__ counts,
                                                       int E, int nblocks, int NB) {
    __shared__ int hist[MAXNB];
    const int b = blockIdx.x;
    for (int t = threadIdx.x; t < NB; t += 256) hist[t] = 0;
    __syncthreads();
    const int beg = b * CHUNK;
    const int end = min(E, beg + CHUNK);
    for (int e = beg + threadIdx.x; e < end; e += 256)
        atomicAdd(&hist[dst[e] >> NB_SHIFT], 1);
    __syncthreads();
    for (int t = threadIdx.x; t < NB; t += 256)
        counts[t * nblocks + b] = hist[t];
}

__global__ __launch_bounds__(256) void scan1_kernel(const int* __restrict__ in,
                                                    int* __restrict__ out,
                                                    int* __restrict__ bsum, int n) {
    __shared__ int s[256];
    int b = blockIdx.x, t = threadIdx.x;
    int base = b * 1024 + t * 4;
    int v0 = 0, v1 = 0, v2 = 0, v3 = 0;
    if (base + 0 < n) v0 = in[base + 0];
    if (base + 1 < n) v1 = in[base + 1];
    if (base + 2 < n) v2 = in[base + 2];
    if (base + 3 < n) v3 = in[base + 3];
    int tsum = v0 + v1 + v2 + v3;
    s[t] = tsum;
    __syncthreads();
    for (int off = 1; off < 256; off <<= 1) {
        int x = (t >= off) ? s[t - off] : 0;
        __syncthreads();
        s[t] += x;
        __syncthreads();
    }
    int excl = s[t] - tsum;
    if (base + 0 < n) out[base + 0] = excl;
    if (base + 1 < n) out[base + 1] = excl + v0;
    if (base + 2 < n) out[base + 2] = excl + v0 + v1;
    if (base + 3 < n) out[base + 3] = excl + v0 + v1 + v2;
    if (t == 255) bsum[b] = s[255];
}

__global__ __launch_bounds__(1024) void scan2_kernel(int* __restrict__ bsum, int nb) {
    __shared__ int s[1024];
    int t = threadIdx.x;
    int v = (t < nb) ? bsum[t] : 0;
    s[t] = v;
    __syncthreads();
    for (int off = 1; off < 1024; off <<= 1) {
        int x = (t >= off) ? s[t - off] : 0;
        __syncthreads();
        s[t] += x;
        __syncthreads();
    }
    if (t < nb) bsum[t] = s[t] - v;   // exclusive
}

__global__ void scan3_kernel(int* __restrict__ out, const int* __restrict__ bsum, int n) {
    int i = blockIdx.x * blockDim.x + threadIdx.x;
    if (i < n) out[i] += bsum[i >> 10];
}

// LDS-staged binscatter: counting-sort the chunk in LDS, write each
// (bucket,chunk) segment contiguously as packed 4B words (src<<8 | dst&255).
__global__ __launch_bounds__(1024) void binscatter_kernel(const int* __restrict__ src,
                                                          const int* __restrict__ dst,
                                                          const int* __restrict__ offsets,
                                                          int* __restrict__ binned,
                                                          int E, int nblocks, int NB) {
    __shared__ int  lhist[1024];
    __shared__ int  lbase[1024];
    __shared__ int  cur[1024];
    __shared__ int  goff[MAXNB];
    __shared__ int2 staged[CHUNK];
    const int b = blockIdx.x, t = threadIdx.x;
    const int beg = b * CHUNK;
    const int end = min(E, beg + CHUNK);
    const int ne  = end - beg;

    lhist[t] = 0;
    for (int k = t; k < NB; k += 1024) goff[k] = offsets[k * nblocks + b];
    __syncthreads();

    int2 regs[8];
    #pragma unroll
    for (int j = 0; j < 8; j++) {
        int e = beg + t + j * 1024;
        if (e < end) {
            regs[j] = make_int2(src[e], dst[e]);
            atomicAdd(&lhist[regs[j].y >> NB_SHIFT], 1);
        }
    }
    __syncthreads();

    int hv = lhist[t];
    for (int off = 1; off < 1024; off <<= 1) {
        int x = (t >= off) ? lhist[t - off] : 0;
        __syncthreads();
        lhist[t] += x;
        __syncthreads();
    }
    lbase[t] = lhist[t] - hv;
    cur[t]   = lhist[t] - hv;
    __syncthreads();

    #pragma unroll
    for (int j = 0; j < 8; j++) {
        int e = beg + t + j * 1024;
        if (e < end) {
            int pos = atomicAdd(&cur[regs[j].y >> NB_SHIFT], 1);
            staged[pos] = regs[j];
        }
    }
    __syncthreads();

    #pragma unroll
    for (int j = 0; j < 8; j++) {
        int tt = t + j * 1024;
        if (tt < ne) {
            int2 sd = staged[tt];
            int bkt = sd.y >> NB_SHIFT;
            binned[goff[bkt] + (tt - lbase[bkt])] = (sd.x << 8) | (sd.y & 255);
        }
    }
}

// one WG per 256-node bucket: local degree hist -> local scan -> dis/rowptr_end
// -> place col within the bucket's window.  binned words: src<<8 | dstlow.
__global__ __launch_bounds__(256) void csrbuild_kernel(const int* __restrict__ binned,
                                                       const int* __restrict__ offsets,
                                                       int* __restrict__ rowptr_end,
                                                       int* __restrict__ colA,
                                                       float* __restrict__ dis,
                                                       int E, int nblocks, int NB, int n) {
    __shared__ int deg[256];
    __shared__ int sc[256];
    __shared__ int cur[256];
    const int b = blockIdx.x;
    const int t = threadIdx.x;
    const int base = offsets[b * nblocks];
    const int bend = (b + 1 < NB) ? offsets[(b + 1) * nblocks] : E;

    deg[t] = 0;
    __syncthreads();
    for (int e = base + t; e < bend; e += 256)
        atomicAdd(&deg[binned[e] & 255], 1);
    __syncthreads();

    int v = deg[t];
    sc[t] = v;
    __syncthreads();
    for (int off = 1; off < 256; off <<= 1) {
        int x = (t >= off) ? sc[t - off] : 0;
        __syncthreads();
        sc[t] += x;
        __syncthreads();
    }
    int incl = sc[t];
    int node = (b << NB_SHIFT) + t;
    if (node < n) {
        rowptr_end[node] = base + incl;
        dis[node] = rsqrtf((float)v + 1.0f);
    }
    cur[t] = base + incl - v;
    __syncthreads();

    for (int e = base + t; e < bend; e += 256) {
        int w = binned[e];
        int pos = atomicAdd(&cur[w & 255], 1);
        colA[pos] = w >> 8;
    }
}

// ==================== weight prep: fragment-major packing ====================
// Chunk c holds 8 halfs (j=0..7) of B[n][k] with l16=c&15, quad=(c>>4)&3,
// (ks,nt) from c>>6; k = ks*32+quad*8+j, n = nt*16+l16.  A wave's B-fragment
// load (lane = quad*16+l16) is then one fully-coalesced 1KB dwordx4 stream.
__global__ void wprep_kernel(const float* __restrict__ W1,
                             const float* __restrict__ Wmu,
                             const float* __restrict__ Wvar,
                             half_t* __restrict__ W1p,
                             half_t* __restrict__ Wcp) {
    int i = blockIdx.x * blockDim.x + threadIdx.x;
    if (i < 32768) {                        // gemm1 pack: K=256, 8 ks
        int c = i >> 3, j = i & 7;
        int l16 = c & 15, quad = (c >> 4) & 3, cc = c >> 6;
        int ks = cc & 7, nt = cc >> 3;
        int k = ks * 32 + quad * 8 + j, nn = nt * 16 + l16;
        W1p[i] = (half_t)W1[k * 128 + nn];
    } else if (i < 49152) {                 // gemm2 pack: K=128, 4 ks
        int i2 = i - 32768;
        int c = i2 >> 3, j = i2 & 7;
        int l16 = c & 15, quad = (c >> 4) & 3, cc = c >> 6;
        int ks = cc & 3, nt = cc >> 2;
        int k = ks * 32 + quad * 8 + j, nn = nt * 16 + l16;
        float v = (nn < DOUT) ? Wmu[k * DOUT + nn] : Wvar[k * DOUT + (nn - DOUT)];
        Wcp[i2] = (half_t)v;
    }
}

// ==================== GEMM1: barrier-free, no LDS ====================
// hs[M,128](fp16) = (A[M,256](fp32) @ W1^T-pack) * dis[row].
// Wave = 16 rows; lane loads its whole A row into regs (16 dwordx4, MLP);
// B fragments stream from L2 (64KB resident).
__global__ __launch_bounds__(256, 3) void gemm1_mfma(const float* __restrict__ A,
                                                     const half_t* __restrict__ Bp,
                                                     const float* __restrict__ dis,
                                                     half_t* __restrict__ C, int M) {
    const int tid = threadIdx.x;
    const int wave = tid >> 6, lane = tid & 63;
    const int l16 = lane & 15, quad = lane >> 4;
    const int mbase = blockIdx.x * 64 + wave * 16;
    int arow = mbase + l16; if (arow >= M) arow = M - 1;
    const float4* Arow = (const float4*)(A + (size_t)arow * 256);

    float4 a[16];
    #pragma unroll
    for (int ks = 0; ks < 8; ks++) {
        a[2 * ks]     = Arow[ks * 8 + quad * 2];
        a[2 * ks + 1] = Arow[ks * 8 + quad * 2 + 1];
    }

    f32x4 acc[8] = {};
    #pragma unroll
    for (int ks = 0; ks < 8; ks++) {
        float4 lo = a[2 * ks], hi = a[2 * ks + 1];
        f16x8 af = { (half_t)lo.x, (half_t)lo.y, (half_t)lo.z, (half_t)lo.w,
                     (half_t)hi.x, (half_t)hi.y, (half_t)hi.z, (half_t)hi.w };
        #pragma unroll
        for (int nt = 0; nt < 8; nt++) {
            f16x8 bf = *(const f16x8*)(Bp + (size_t)((nt * 8 + ks) * 64 + lane) * 8);
            acc[nt] = __builtin_amdgcn_mfma_f32_16x16x32_f16(af, bf, acc[nt], 0, 0, 0);
        }
    }

    #pragma unroll
    for (int r = 0; r < 4; r++) {
        int row = mbase + quad * 4 + r;
        if (row < M) {
            float d = dis[row];
            #pragma unroll
            for (int nt = 0; nt < 8; nt++)
                C[(size_t)row * 128 + nt * 16 + l16] = (half_t)(acc[nt][r] * d);
        }
    }
}

// ==================== GEMM2: barrier-free, no LDS ====================
// [mu|sig][M,64](fp32) = A[M,128](fp16) @ Wcat-pack + bias.
__global__ __launch_bounds__(256, 3) void gemm2_mfma(const half_t* __restrict__ A,
                                                     const half_t* __restrict__ Bp,
                                                     const float* __restrict__ bmu,
                                                     const float* __restrict__ bvar,
                                                     float* __restrict__ out_mu,
                                                     float* __restrict__ out_sig, int M) {
    const int tid = threadIdx.x;
    const int wave = tid >> 6, lane = tid & 63;
    const int l16 = lane & 15, quad = lane >> 4;
    const int mbase = blockIdx.x * 64 + wave * 16;
    int arow = mbase + l16; if (arow >= M) arow = M - 1;
    const f16x8* Arow = (const f16x8*)(A + (size_t)arow * 128);

    f16x8 a[4];
    #pragma unroll
    for (int ks = 0; ks < 4; ks++) a[ks] = Arow[ks * 4 + quad];

    f32x4 acc[8] = {};
    #pragma unroll
    for (int ks = 0; ks < 4; ks++) {
        #pragma unroll
        for (int nt = 0; nt < 8; nt++) {
            f16x8 bf = *(const f16x8*)(Bp + (size_t)((nt * 4 + ks) * 64 + lane) * 8);
            acc[nt] = __builtin_amdgcn_mfma_f32_16x16x32_f16(a[ks], bf, acc[nt], 0, 0, 0);
        }
    }

    #pragma unroll
    for (int r = 0; r < 4; r++) {
        int row = mbase + quad * 4 + r;
        if (row < M) {
            #pragma unroll
            for (int nt = 0; nt < 8; nt++) {
                int col = nt * 16 + l16;
                float bias = (col < DOUT) ? bmu[col] : bvar[col - DOUT];
                float v = acc[nt][r] + bias;
                if (col < DOUT) out_mu[(size_t)row * DOUT + col] = v;
                else            out_sig[(size_t)row * DOUT + (col - DOUT)] = v;
            }
        }
    }
}

// ==================== aggregation on pre-scaled features ====================
// acc_i = hin[i] + sum_{s in N(i)} hin[s]          (one gather per edge)
// LAYER1: hout = relu(di*acc + b1)*di   LAYER2: hout = di*acc
template <bool LAYER1>
__global__ __launch_bounds__(256) void agg_kernel(const int* __restrict__ rowptr_end,
                                                  const int* __restrict__ col,
                                                  const float* __restrict__ dis,
                                                  const half_t* __restrict__ hin,
                                                  half_t* __restrict__ hout,
                                                  const float* __restrict__ bias, int n) {
    int node = blockIdx.x * 8 + (threadIdx.x >> 5);
    if (node >= n) return;
    int lane = threadIdx.x & 31;
    int beg = (node == 0) ? 0 : rowptr_end[node - 1];
    int end = rowptr_end[node];
    const f16x4* hv = (const f16x4*)hin;

    f16x4 sv = hv[(size_t)node * 32 + lane];
    float ax = (float)sv[0], ay = (float)sv[1], az = (float)sv[2], aw = (float)sv[3];

    int e = beg;
    for (; e + 7 < end; e += 8) {
        int s0 = col[e],     s1 = col[e + 1], s2 = col[e + 2], s3 = col[e + 3];
        int s4 = col[e + 4], s5 = col[e + 5], s6 = col[e + 6], s7 = col[e + 7];
        f16x4 v0 = hv[(size_t)s0 * 32 + lane];
        f16x4 v1 = hv[(size_t)s1 * 32 + lane];
        f16x4 v2 = hv[(size_t)s2 * 32 + lane];
        f16x4 v3 = hv[(size_t)s3 * 32 + lane];
        f16x4 v4 = hv[(size_t)s4 * 32 + lane];
        f16x4 v5 = hv[(size_t)s5 * 32 + lane];
        f16x4 v6 = hv[(size_t)s6 * 32 + lane];
        f16x4 v7 = hv[(size_t)s7 * 32 + lane];
        ax += ((float)v0[0] + (float)v1[0] + (float)v2[0] + (float)v3[0]) +
              ((float)v4[0] + (float)v5[0] + (float)v6[0] + (float)v7[0]);
        ay += ((float)v0[1] + (float)v1[1] + (float)v2[1] + (float)v3[1]) +
              ((float)v4[1] + (float)v5[1] + (float)v6[1] + (float)v7[1]);
        az += ((float)v0[2] + (float)v1[2] + (float)v2[2] + (float)v3[2]) +
              ((float)v4[2] + (float)v5[2] + (float)v6[2] + (float)v7[2]);
        aw += ((float)v0[3] + (float)v1[3] + (float)v2[3] + (float)v3[3]) +
              ((float)v4[3] + (float)v5[3] + (float)v6[3] + (float)v7[3]);
    }
    for (; e < end; e++) {
        int s0 = col[e];
        f16x4 v0 = hv[(size_t)s0 * 32 + lane];
        ax += (float)v0[0]; ay += (float)v0[1]; az += (float)v0[2]; aw += (float)v0[3];
    }

    float di = dis[node];
    if (LAYER1) {
        const float4 b = ((const float4*)bias)[lane];
        ax = ax * di + b.x; ay = ay * di + b.y; az = az * di + b.z; aw = aw * di + b.w;
        ax = (ax > 0.f ? ax : 0.f) * di;
        ay = (ay > 0.f ? ay : 0.f) * di;
        az = (az > 0.f ? az : 0.f) * di;
        aw = (aw > 0.f ? aw : 0.f) * di;
    } else {
        ax *= di; ay *= di; az *= di; aw *= di;
    }
    f16x4 o = { (half_t)ax, (half_t)ay, (half_t)az, (half_t)aw };
    ((f16x4*)hout)[(size_t)node * 32 + lane] = o;
}

extern "C" void kernel_launch(void* const* d_in, const int* in_sizes, int n_in,
                              void* d_out, int out_size, void* d_ws, size_t ws_size,
                              hipStream_t stream) {
    const float* x    = (const float*)d_in[0];
    const int*   ei   = (const int*)d_in[1];
    const float* W1   = (const float*)d_in[2];
    const float* b1   = (const float*)d_in[3];
    const float* Wmu  = (const float*)d_in[4];
    const float* bmu  = (const float*)d_in[5];
    const float* Wvar = (const float*)d_in[6];
    const float* bvar = (const float*)d_in[7];

    const int n = in_sizes[0] / 256;     // 100000
    const int E = in_sizes[1] / 2;       // 1600000
    const int* src = ei;
    const int* dst = ei + E;

    const int NB      = (n + 255) >> NB_SHIFT;       // 391
    const int nblocks = (E + CHUNK - 1) / CHUNK;     // 196
    const int flat    = NB * nblocks;
    const int nb_scan = (flat + 1023) / 1024;        // 75 (<= 1024)

    char* ws = (char*)d_ws;
    size_t off = 0;
    auto alloc = [&](size_t bytes) { void* p = ws + off; off = (off + bytes + 255) & ~(size_t)255; return p; };
    float*  dis     = (float*) alloc((size_t)n * 4);
    int*    rowptr  = (int*)   alloc((size_t)n * 4);
    int*    counts  = (int*)   alloc((size_t)flat * 4);
    int*    offsets = (int*)   alloc((size_t)flat * 4);
    int*    bsum    = (int*)   alloc((size_t)nb_scan * 4 + 256);
    int*    binned  = (int*)   alloc((size_t)E * 4);
    int*    col     = (int*)   alloc((size_t)E * 4);
    half_t* W1p     = (half_t*)alloc((size_t)256 * HID * 2);
    half_t* Wcp     = (half_t*)alloc((size_t)HID * HID * 2);
    half_t* hs      = (half_t*)alloc((size_t)n * HID * 2);  // gemm1 out (pre-scaled); reused as agg2
    half_t* h1s     = (half_t*)alloc((size_t)n * HID * 2);  // relu out (pre-scaled)
    half_t* agg2    = hs;                                   // alias: hs dead after agg1

    float* out_mu  = (float*)d_out;
    float* out_sig = (float*)d_out + (size_t)n * DOUT;

    // CSR build
    bincount_kernel<<<nblocks, 256, 0, stream>>>(dst, counts, E, nblocks, NB);
    scan1_kernel<<<nb_scan, 256, 0, stream>>>(counts, offsets, bsum, flat);
    scan2_kernel<<<1, 1024, 0, stream>>>(bsum, nb_scan);
    scan3_kernel<<<(flat + 255) / 256, 256, 0, stream>>>(offsets, bsum, flat);
    binscatter_kernel<<<nblocks, 1024, 0, stream>>>(src, dst, offsets, binned, E, nblocks, NB);
    csrbuild_kernel<<<NB, 256, 0, stream>>>(binned, offsets, rowptr, col, dis, E, nblocks, NB, n);

    // weights (fragment-major pack)
    wprep_kernel<<<192, 256, 0, stream>>>(W1, Wmu, Wvar, W1p, Wcp);

    // dense + sparse pipeline
    gemm1_mfma<<<(n + 63) / 64, 256, 0, stream>>>(x, W1p, dis, hs, n);
    agg_kernel<true><<<(n + 7) / 8, 256, 0, stream>>>(rowptr, col, dis, hs, h1s, b1, n);
    agg_kernel<false><<<(n + 7) / 8, 256, 0, stream>>>(rowptr, col, dis, h1s, agg2, nullptr, n);
    gemm2_mfma<<<(n + 63) / 64, 256, 0, stream>>>(agg2, Wcp, bmu, bvar, out_mu, out_sig, n);
}